// Round 2
// baseline (461.733 us; speedup 1.0000x reference)
//
#include <hip/hip_runtime.h>
#include <cstdint>
#include <cstddef>

#define BB  2
#define TT  2048
#define CC  1024
#define NHH 16
#define HSS 64
#define BT  (BB*TT)   // 4096

typedef unsigned short u16;
typedef __attribute__((ext_vector_type(8))) __bf16 bf16x8;
typedef __attribute__((ext_vector_type(4))) float f32x4;

__device__ __forceinline__ u16 f2bf(float f) {
    union { float f; unsigned int u; } x; x.f = f;
    return (u16)((x.u + 0x7fffu + ((x.u >> 16) & 1u)) >> 16);
}
__device__ __forceinline__ float bf2f(u16 v) {
    union { unsigned int u; float f; } x; x.u = ((unsigned int)v) << 16;
    return x.f;
}

#define MFMA(a,b,c) __builtin_amdgcn_mfma_f32_16x16x32_bf16((a),(b),(c),0,0,0)

// ---------------------------------------------------------------------------
// proj_kernel: Out_f32 = X @ W + bias.  z=0 -> K (split bf16x3, ~fp32 exact),
// z=1 -> V (plain bf16 hi-only; error enters output linearly, negligible).
// M=4096, N=1024, K=1024. 64x64 tile per block, 4 waves of 32x32.
// ---------------------------------------------------------------------------
__global__ __launch_bounds__(256) void proj_kernel(
    const float* __restrict__ X,
    const float* __restrict__ Wk, const float* __restrict__ bk,
    const float* __restrict__ Wv, const float* __restrict__ bv,
    float* __restrict__ Kw, float* __restrict__ Vw)
{
    const bool split  = (blockIdx.z == 0);
    const float* W    = split ? Wk : Wv;
    const float* bias = split ? bk : bv;
    float* Out        = split ? Kw : Vw;

    __shared__ __align__(16) u16 Ah[64][40];
    __shared__ __align__(16) u16 Al[64][40];
    __shared__ __align__(16) u16 Bh[64][40];
    __shared__ __align__(16) u16 Bl[64][40];

    const int tid  = threadIdx.x;
    const int m0   = blockIdx.y * 64, n0 = blockIdx.x * 64;
    const int w    = tid >> 6, lane = tid & 63;
    const int quad = lane >> 4, l15 = lane & 15;
    const int wm   = (w >> 1) * 32, wn = (w & 1) * 32;
    const int amm  = tid >> 2, ako = (tid & 3) * 8;   // A: 64 rows x 32 k
    const int bkk  = tid >> 3, bn0 = (tid & 7) * 8;   // B: 32 k-rows x 64 n

    f32x4 acc[2][2] = {};

    for (int k0 = 0; k0 < CC; k0 += 32) {
        {   // stage A hi/lo
            const float* g = &X[(size_t)(m0 + amm) * CC + k0 + ako];
            union { uint4 u; u16 s[8]; } H, L;
            #pragma unroll
            for (int u = 0; u < 8; ++u) {
                float v = g[u];
                u16 h = f2bf(v);
                H.s[u] = h; L.s[u] = f2bf(v - bf2f(h));
            }
            *(uint4*)&Ah[amm][ako] = H.u;
            *(uint4*)&Al[amm][ako] = L.u;
        }
        {   // stage B transposed hi/lo: Bs[n][k] = W[k][n]
            const float* g = &W[(size_t)(k0 + bkk) * CC + n0 + bn0];
            #pragma unroll
            for (int u = 0; u < 8; ++u) {
                float v = g[u];
                u16 h = f2bf(v);
                Bh[bn0 + u][bkk] = h;
                Bl[bn0 + u][bkk] = f2bf(v - bf2f(h));
            }
        }
        __syncthreads();

        bf16x8 a0h = *(const bf16x8*)&Ah[wm + l15][quad * 8];
        bf16x8 a1h = *(const bf16x8*)&Ah[wm + 16 + l15][quad * 8];
        bf16x8 b0h = *(const bf16x8*)&Bh[wn + l15][quad * 8];
        bf16x8 b1h = *(const bf16x8*)&Bh[wn + 16 + l15][quad * 8];
        acc[0][0] = MFMA(a0h, b0h, acc[0][0]);
        acc[0][1] = MFMA(a0h, b1h, acc[0][1]);
        acc[1][0] = MFMA(a1h, b0h, acc[1][0]);
        acc[1][1] = MFMA(a1h, b1h, acc[1][1]);
        if (split) {
            bf16x8 a0l = *(const bf16x8*)&Al[wm + l15][quad * 8];
            bf16x8 a1l = *(const bf16x8*)&Al[wm + 16 + l15][quad * 8];
            bf16x8 b0l = *(const bf16x8*)&Bl[wn + l15][quad * 8];
            bf16x8 b1l = *(const bf16x8*)&Bl[wn + 16 + l15][quad * 8];
            acc[0][0] = MFMA(a0h, b0l, acc[0][0]);
            acc[0][0] = MFMA(a0l, b0h, acc[0][0]);
            acc[0][1] = MFMA(a0h, b1l, acc[0][1]);
            acc[0][1] = MFMA(a0l, b1h, acc[0][1]);
            acc[1][0] = MFMA(a1h, b0l, acc[1][0]);
            acc[1][0] = MFMA(a1l, b0h, acc[1][0]);
            acc[1][1] = MFMA(a1h, b1l, acc[1][1]);
            acc[1][1] = MFMA(a1l, b1h, acc[1][1]);
        }
        __syncthreads();
    }

    #pragma unroll
    for (int ci = 0; ci < 2; ++ci) {
        const int col = n0 + wn + ci * 16 + l15;
        const float bv_ = bias[col];
        #pragma unroll
        for (int ri = 0; ri < 2; ++ri) {
            const int rbase = m0 + wm + ri * 16 + quad * 4;
            #pragma unroll
            for (int r = 0; r < 4; ++r)
                Out[(size_t)(rbase + r) * CC + col] = acc[ri][ci][r] + bv_;
        }
    }
}

// ---------------------------------------------------------------------------
// attn_kernel: flash attention, fp32 in/out.
// scores S[i][j] = Kproj[i,:] . X[j,:] in split-bf16x3 (near-fp32 exact).
// Block = (b, h, 64-row i-tile), 4 waves; wave w owns i-rows [w*16, w*16+16).
// ---------------------------------------------------------------------------
__global__ __launch_bounds__(256) void attn_kernel(
    const float* __restrict__ X, const float* __restrict__ Kw,
    const float* __restrict__ Vw, float* __restrict__ out)
{
    const int it = blockIdx.x, h = blockIdx.y, b = blockIdx.z;

    __shared__ __align__(16) u16 Qh[64][72], Ql[64][72];   // Kproj rows hi/lo
    __shared__ __align__(16) u16 Kh[64][72], Kl[64][72];   // x rows hi/lo
    __shared__ __align__(16) u16 Vs[64][72];               // V transposed [d][j]
    __shared__ __align__(16) u16 Ps[4][16][72];            // per-wave P tile

    const int tid  = threadIdx.x;
    const int w    = tid >> 6, lane = tid & 63;
    const int quad = lane >> 4, l15 = lane & 15;
    const int i0   = it * 64;
    const size_t rowbase = (size_t)b * TT;
    const int hd = h * HSS;

    // load Q tile (projected K rows) hi/lo
    #pragma unroll
    for (int rep = 0; rep < 2; ++rep) {
        const int idx = tid + rep * 256;
        const int ii = idx >> 3, dof = (idx & 7) * 8;
        const float* g = &Kw[(rowbase + i0 + ii) * CC + hd + dof];
        union { uint4 u; u16 s[8]; } H, L;
        #pragma unroll
        for (int u = 0; u < 8; ++u) {
            float v = g[u];
            u16 hh = f2bf(v);
            H.s[u] = hh; L.s[u] = f2bf(v - bf2f(hh));
        }
        *(uint4*)&Qh[ii][dof] = H.u;
        *(uint4*)&Ql[ii][dof] = L.u;
    }

    float mrow[4], lrow[4];
    f32x4 o[4] = {};
    #pragma unroll
    for (int r = 0; r < 4; ++r) { mrow[r] = -1e30f; lrow[r] = 0.f; }

    for (int jt = 0; jt <= it; ++jt) {
        const int j0 = jt * 64;
        #pragma unroll
        for (int rep = 0; rep < 2; ++rep) {
            const int idx = tid + rep * 256;
            const int jj = idx >> 3, dof = (idx & 7) * 8;
            {   // x rows hi/lo
                const float* g = &X[(rowbase + j0 + jj) * CC + hd + dof];
                union { uint4 u; u16 s[8]; } H, L;
                #pragma unroll
                for (int u = 0; u < 8; ++u) {
                    float v = g[u];
                    u16 hh = f2bf(v);
                    H.s[u] = hh; L.s[u] = f2bf(v - bf2f(hh));
                }
                *(uint4*)&Kh[jj][dof] = H.u;
                *(uint4*)&Kl[jj][dof] = L.u;
            }
            {   // V transposed, hi only
                const float* g = &Vw[(rowbase + j0 + jj) * CC + hd + dof];
                #pragma unroll
                for (int u = 0; u < 8; ++u) Vs[dof + u][jj] = f2bf(g[u]);
            }
        }
        __syncthreads();

        bf16x8 aqh0 = *(const bf16x8*)&Qh[w * 16 + l15][quad * 8];
        bf16x8 aqh1 = *(const bf16x8*)&Qh[w * 16 + l15][32 + quad * 8];
        bf16x8 aql0 = *(const bf16x8*)&Ql[w * 16 + l15][quad * 8];
        bf16x8 aql1 = *(const bf16x8*)&Ql[w * 16 + l15][32 + quad * 8];
        f32x4 s[4];
        #pragma unroll
        for (int nt = 0; nt < 4; ++nt) {
            bf16x8 bkh0 = *(const bf16x8*)&Kh[nt * 16 + l15][quad * 8];
            bf16x8 bkh1 = *(const bf16x8*)&Kh[nt * 16 + l15][32 + quad * 8];
            bf16x8 bkl0 = *(const bf16x8*)&Kl[nt * 16 + l15][quad * 8];
            bf16x8 bkl1 = *(const bf16x8*)&Kl[nt * 16 + l15][32 + quad * 8];
            f32x4 z = {};
            z = MFMA(aqh0, bkl0, z);
            z = MFMA(aql0, bkh0, z);
            z = MFMA(aqh0, bkh0, z);
            z = MFMA(aqh1, bkl1, z);
            z = MFMA(aql1, bkh1, z);
            z = MFMA(aqh1, bkh1, z);
            s[nt] = z;
        }

        if (jt == it) {  // causal mask on diagonal tile
            #pragma unroll
            for (int nt = 0; nt < 4; ++nt) {
                const int jg = j0 + nt * 16 + l15;
                #pragma unroll
                for (int r = 0; r < 4; ++r) {
                    const int ig = i0 + w * 16 + quad * 4 + r;
                    if (jg > ig) s[nt][r] = -1e30f;
                }
            }
        }

        float alpha[4];
        #pragma unroll
        for (int r = 0; r < 4; ++r) {
            float mx = fmaxf(fmaxf(s[0][r], s[1][r]), fmaxf(s[2][r], s[3][r]));
            #pragma unroll
            for (int off = 1; off < 16; off <<= 1)
                mx = fmaxf(mx, __shfl_xor(mx, off, 64));
            const float mnew = fmaxf(mrow[r], mx);
            alpha[r] = __expf(mrow[r] - mnew);
            mrow[r] = mnew;
            float psum = 0.f;
            #pragma unroll
            for (int nt = 0; nt < 4; ++nt) {
                const float p = __expf(s[nt][r] - mnew);
                s[nt][r] = p;
                psum += p;
            }
            #pragma unroll
            for (int off = 1; off < 16; off <<= 1)
                psum += __shfl_xor(psum, off, 64);
            lrow[r] = lrow[r] * alpha[r] + psum;
        }
        #pragma unroll
        for (int dt = 0; dt < 4; ++dt)
            #pragma unroll
            for (int r = 0; r < 4; ++r)
                o[dt][r] *= alpha[r];

        // P: C/D layout -> LDS -> A layout
        #pragma unroll
        for (int nt = 0; nt < 4; ++nt)
            #pragma unroll
            for (int r = 0; r < 4; ++r)
                Ps[w][quad * 4 + r][nt * 16 + l15] = f2bf(s[nt][r]);
        __syncthreads();

        bf16x8 ap0 = *(const bf16x8*)&Ps[w][l15][quad * 8];
        bf16x8 ap1 = *(const bf16x8*)&Ps[w][l15][32 + quad * 8];
        #pragma unroll
        for (int dt = 0; dt < 4; ++dt) {
            bf16x8 bv0 = *(const bf16x8*)&Vs[dt * 16 + l15][quad * 8];
            bf16x8 bv1 = *(const bf16x8*)&Vs[dt * 16 + l15][32 + quad * 8];
            o[dt] = MFMA(ap0, bv0, o[dt]);
            o[dt] = MFMA(ap1, bv1, o[dt]);
        }
        __syncthreads();
    }

    #pragma unroll
    for (int dt = 0; dt < 4; ++dt) {
        #pragma unroll
        for (int r = 0; r < 4; ++r) {
            const int ig = i0 + w * 16 + quad * 4 + r;
            out[(rowbase + ig) * CC + hd + dt * 16 + l15] = o[dt][r] / lrow[r];
        }
    }
}

extern "C" void kernel_launch(void* const* d_in, const int* in_sizes, int n_in,
                              void* d_out, int out_size, void* d_ws, size_t ws_size,
                              hipStream_t stream) {
    (void)in_sizes; (void)n_in; (void)out_size; (void)ws_size;
    const float* x  = (const float*)d_in[0];
    const float* Wk = (const float*)d_in[1];
    const float* bk = (const float*)d_in[2];
    const float* Wv = (const float*)d_in[3];
    const float* bv = (const float*)d_in[4];
    float* out = (float*)d_out;

    float* Kw = (float*)d_ws;                   // 4096*1024 fp32 = 16 MB
    float* Vw = Kw + (size_t)BT * CC;           // 16 MB

    dim3 pg(CC / 64, BT / 64, 2);               // (16, 64, 2)
    proj_kernel<<<pg, 256, 0, stream>>>(x, Wk, bk, Wv, bv, Kw, Vw);

    dim3 ag(TT / 64, NHH, BB);                  // (32, 16, 2)
    attn_kernel<<<ag, 256, 0, stream>>>(x, Kw, Vw, out);
}

// Round 3
// 225.576 us; speedup vs baseline: 2.0469x; 2.0469x over previous
//
#include <hip/hip_runtime.h>
#include <cstdint>
#include <cstddef>

#define BB  2
#define TT  2048
#define CC  1024
#define NHH 16
#define HSS 64
#define BT  (BB*TT)   // 4096

typedef unsigned short u16;
typedef __attribute__((ext_vector_type(8))) __bf16 bf16x8;
typedef __attribute__((ext_vector_type(4))) float f32x4;

__device__ __forceinline__ u16 f2bf(float f) {
    union { float f; unsigned int u; } x; x.f = f;
    return (u16)((x.u + 0x7fffu + ((x.u >> 16) & 1u)) >> 16);
}
__device__ __forceinline__ float bf2f(u16 v) {
    union { unsigned int u; float f; } x; x.u = ((unsigned int)v) << 16;
    return x.f;
}

#define MFMA(a,b,c) __builtin_amdgcn_mfma_f32_16x16x32_bf16((a),(b),(c),0,0,0)

// ---------------------------------------------------------------------------
// convert_x: x fp32 -> Xh, Xl bf16 (hi + residual-lo), elementwise.
// ---------------------------------------------------------------------------
__global__ __launch_bounds__(256) void convert_x(
    const float* __restrict__ X, u16* __restrict__ Xh, u16* __restrict__ Xl)
{
    const int idx = (blockIdx.x * 256 + threadIdx.x) * 8;
    const float4 a = *(const float4*)&X[idx];
    const float4 b = *(const float4*)&X[idx + 4];
    float v[8] = {a.x, a.y, a.z, a.w, b.x, b.y, b.z, b.w};
    union { uint4 u; u16 s[8]; } H, L;
    #pragma unroll
    for (int u = 0; u < 8; ++u) {
        u16 h = f2bf(v[u]);
        H.s[u] = h; L.s[u] = f2bf(v[u] - bf2f(h));
    }
    *(uint4*)&Xh[idx] = H.u;
    *(uint4*)&Xl[idx] = L.u;
}

// ---------------------------------------------------------------------------
// convert_w: W [k][n] fp32 -> WT [n][k] bf16 (Wk: hi+lo, Wv: hi only).
// 64x64 tile via LDS transpose, coalesced global in/out.
// ---------------------------------------------------------------------------
__global__ __launch_bounds__(256) void convert_w(
    const float* __restrict__ Wk, const float* __restrict__ Wv,
    u16* __restrict__ WkTh, u16* __restrict__ WkTl, u16* __restrict__ WvTh)
{
    const bool isK = (blockIdx.z == 0);
    const float* W = isK ? Wk : Wv;
    __shared__ __align__(16) u16 LH[64][72];
    __shared__ __align__(16) u16 LL[64][72];
    const int tid = threadIdx.x;
    const int k0 = blockIdx.y * 64, n0 = blockIdx.x * 64;
    {
        const int row = tid >> 2, coff = (tid & 3) * 16;
        const float* g = &W[(size_t)(k0 + row) * CC + n0 + coff];
        #pragma unroll
        for (int u = 0; u < 16; ++u) {
            float v = g[u];
            u16 h = f2bf(v);
            LH[row][coff + u] = h;
            LL[row][coff + u] = f2bf(v - bf2f(h));
        }
    }
    __syncthreads();
    {
        const int n = tid >> 2, kc = (tid & 3) * 16;
        union { uint4 u[2]; u16 s[16]; } Hq, Lq;
        #pragma unroll
        for (int u = 0; u < 16; ++u) {
            Hq.s[u] = LH[kc + u][n];
            Lq.s[u] = LL[kc + u][n];
        }
        u16* dh = isK ? WkTh : WvTh;
        uint4* ph = (uint4*)&dh[(size_t)(n0 + n) * CC + k0 + kc];
        ph[0] = Hq.u[0]; ph[1] = Hq.u[1];
        if (isK) {
            uint4* pl = (uint4*)&WkTl[(size_t)(n0 + n) * CC + k0 + kc];
            pl[0] = Lq.u[0]; pl[1] = Lq.u[1];
        }
    }
}

// ---------------------------------------------------------------------------
// proj_kernel: 128x128 tile bf16 GEMM from pre-converted inputs.
// z=0: Kproj = X @ Wk + bk, split product (hh+hl+lh), output split bf16 Kh/Kl.
// z=1: V = X @ Wv + bv (hi only), output head-transposed Vt[b][h][d][T] bf16.
// ---------------------------------------------------------------------------
__global__ __launch_bounds__(256) void proj_kernel(
    const u16* __restrict__ Xh, const u16* __restrict__ Xl,
    const u16* __restrict__ WkTh, const u16* __restrict__ WkTl,
    const u16* __restrict__ WvTh,
    const float* __restrict__ bk, const float* __restrict__ bv,
    u16* __restrict__ Kh, u16* __restrict__ Kl, u16* __restrict__ Vt)
{
    const bool isK = (blockIdx.z == 0);
    const u16* WTh = isK ? WkTh : WvTh;

    __shared__ __align__(16) u16 Ah[128][40], Bh[128][40];
    __shared__ __align__(16) u16 Al[128][40], Bl[128][40];

    const int tid = threadIdx.x;
    const int m0 = blockIdx.y * 128, n0 = blockIdx.x * 128;
    const int w = tid >> 6, lane = tid & 63;
    const int quad = lane >> 4, l15 = lane & 15;
    const int wm = (w >> 1) * 64, wn = (w & 1) * 64;

    // staging chunk coords: 512 chunks of 16B per 128x32 tile
    const int r0 = tid >> 2, kc0 = (tid & 3) * 8;
    const int r1 = (tid + 256) >> 2, kc1 = ((tid + 256) & 3) * 8;

    f32x4 acc[4][4] = {};

    for (int k0 = 0; k0 < CC; k0 += 32) {
        *(uint4*)&Ah[r0][kc0] = *(const uint4*)&Xh[(size_t)(m0 + r0) * CC + k0 + kc0];
        *(uint4*)&Ah[r1][kc1] = *(const uint4*)&Xh[(size_t)(m0 + r1) * CC + k0 + kc1];
        *(uint4*)&Bh[r0][kc0] = *(const uint4*)&WTh[(size_t)(n0 + r0) * CC + k0 + kc0];
        *(uint4*)&Bh[r1][kc1] = *(const uint4*)&WTh[(size_t)(n0 + r1) * CC + k0 + kc1];
        if (isK) {
            *(uint4*)&Al[r0][kc0] = *(const uint4*)&Xl[(size_t)(m0 + r0) * CC + k0 + kc0];
            *(uint4*)&Al[r1][kc1] = *(const uint4*)&Xl[(size_t)(m0 + r1) * CC + k0 + kc1];
            *(uint4*)&Bl[r0][kc0] = *(const uint4*)&WkTl[(size_t)(n0 + r0) * CC + k0 + kc0];
            *(uint4*)&Bl[r1][kc1] = *(const uint4*)&WkTl[(size_t)(n0 + r1) * CC + k0 + kc1];
        }
        __syncthreads();

        bf16x8 ah[4], al[4];
        #pragma unroll
        for (int i = 0; i < 4; ++i) {
            ah[i] = *(const bf16x8*)&Ah[wm + i * 16 + l15][quad * 8];
            if (isK) al[i] = *(const bf16x8*)&Al[wm + i * 16 + l15][quad * 8];
        }
        #pragma unroll
        for (int j = 0; j < 4; ++j) {
            bf16x8 bh_ = *(const bf16x8*)&Bh[wn + j * 16 + l15][quad * 8];
            if (isK) {
                bf16x8 bl_ = *(const bf16x8*)&Bl[wn + j * 16 + l15][quad * 8];
                #pragma unroll
                for (int i = 0; i < 4; ++i) {
                    acc[i][j] = MFMA(ah[i], bl_, acc[i][j]);
                    acc[i][j] = MFMA(al[i], bh_, acc[i][j]);
                    acc[i][j] = MFMA(ah[i], bh_, acc[i][j]);
                }
            } else {
                #pragma unroll
                for (int i = 0; i < 4; ++i)
                    acc[i][j] = MFMA(ah[i], bh_, acc[i][j]);
            }
        }
        __syncthreads();
    }

    if (isK) {
        #pragma unroll
        for (int j = 0; j < 4; ++j) {
            const int col = n0 + wn + j * 16 + l15;
            const float bias = bk[col];
            #pragma unroll
            for (int i = 0; i < 4; ++i) {
                const int rowb = m0 + wm + i * 16 + quad * 4;
                #pragma unroll
                for (int r = 0; r < 4; ++r) {
                    const float val = acc[i][j][r] + bias;
                    const u16 h = f2bf(val);
                    Kh[(size_t)(rowb + r) * CC + col] = h;
                    Kl[(size_t)(rowb + r) * CC + col] = f2bf(val - bf2f(h));
                }
            }
        }
    } else {
        #pragma unroll
        for (int j = 0; j < 4; ++j) {
            const int col = n0 + wn + j * 16 + l15;
            const float bias = bv[col];
            const int d = col & (HSS - 1), hh = col >> 6;
            #pragma unroll
            for (int i = 0; i < 4; ++i) {
                const int t0 = m0 + wm + i * 16 + quad * 4;
                const int bb = t0 >> 11, tt = t0 & (TT - 1);
                ushort4 pk;
                pk.x = f2bf(acc[i][j][0] + bias);
                pk.y = f2bf(acc[i][j][1] + bias);
                pk.z = f2bf(acc[i][j][2] + bias);
                pk.w = f2bf(acc[i][j][3] + bias);
                *(ushort4*)&Vt[((size_t)(bb * NHH + hh) * HSS + d) * TT + tt] = pk;
            }
        }
    }
}

// ---------------------------------------------------------------------------
// attn: paired i-tiles (k, 31-k) per block -> uniform 33 tile-units/block.
// Grid (16, NH, B) = 512 blocks = exactly 2/CU. 2 barriers per j-tile,
// register prefetch of next tile, pure vector staging (no conversions).
// ---------------------------------------------------------------------------
__device__ __forceinline__ void online_update(
    f32x4 (&s)[4], float (&m_)[4], float (&l_)[4], f32x4 (&o_)[4],
    u16 (*Psw)[72], const u16 (*Vsr)[72], int quad, int l15)
{
    float alpha[4];
    #pragma unroll
    for (int r = 0; r < 4; ++r) {
        float mx = fmaxf(fmaxf(s[0][r], s[1][r]), fmaxf(s[2][r], s[3][r]));
        #pragma unroll
        for (int off = 1; off < 16; off <<= 1)
            mx = fmaxf(mx, __shfl_xor(mx, off, 64));
        const float mnew = fmaxf(m_[r], mx);
        alpha[r] = __expf(m_[r] - mnew);
        m_[r] = mnew;
        float psum = 0.f;
        #pragma unroll
        for (int nt = 0; nt < 4; ++nt) {
            const float p = __expf(s[nt][r] - mnew);
            s[nt][r] = p; psum += p;
        }
        #pragma unroll
        for (int off = 1; off < 16; off <<= 1)
            psum += __shfl_xor(psum, off, 64);
        l_[r] = l_[r] * alpha[r] + psum;
    }
    #pragma unroll
    for (int nt = 0; nt < 4; ++nt)
        #pragma unroll
        for (int r = 0; r < 4; ++r)
            Psw[quad * 4 + r][nt * 16 + l15] = f2bf(s[nt][r]);
    bf16x8 ap0 = *(const bf16x8*)&Psw[l15][quad * 8];
    bf16x8 ap1 = *(const bf16x8*)&Psw[l15][32 + quad * 8];
    #pragma unroll
    for (int dt = 0; dt < 4; ++dt) {
        bf16x8 bv0 = *(const bf16x8*)&Vsr[dt * 16 + l15][quad * 8];
        bf16x8 bv1 = *(const bf16x8*)&Vsr[dt * 16 + l15][32 + quad * 8];
        f32x4 t = o_[dt];
        #pragma unroll
        for (int r = 0; r < 4; ++r) t[r] *= alpha[r];
        t = MFMA(ap0, bv0, t);
        t = MFMA(ap1, bv1, t);
        o_[dt] = t;
    }
}

__global__ __launch_bounds__(256) void attn_kernel(
    const u16* __restrict__ Xh, const u16* __restrict__ Xl,
    const u16* __restrict__ Kh, const u16* __restrict__ Kl,
    const u16* __restrict__ Vt, float* __restrict__ out)
{
    const int kk = blockIdx.x, h = blockIdx.y, b = blockIdx.z;
    const int iA = kk, iB = 31 - kk;          // iA < iB always
    const int i0A = iA * 64, i0B = iB * 64;

    __shared__ __align__(16) u16 QAh[64][72], QAl[64][72];
    __shared__ __align__(16) u16 QBh[64][72], QBl[64][72];
    __shared__ __align__(16) u16 Ksh[64][72], Ksl[64][72], Vs[64][72];
    __shared__ __align__(16) u16 Ps[4][16][72];

    const int tid = threadIdx.x;
    const int w = tid >> 6, lane = tid & 63;
    const int quad = lane >> 4, l15 = lane & 15;
    const size_t rowbase = (size_t)b * TT;
    const int hd = h * HSS;
    const size_t vbase = (size_t)(b * NHH + h) * HSS * TT;

    // stage both Q tiles (projected-K rows, split)
    #pragma unroll
    for (int rep = 0; rep < 2; ++rep) {
        const int idx = tid + rep * 256;
        const int ii = idx >> 3, dof = (idx & 7) * 8;
        *(uint4*)&QAh[ii][dof] = *(const uint4*)&Kh[(rowbase + i0A + ii) * CC + hd + dof];
        *(uint4*)&QAl[ii][dof] = *(const uint4*)&Kl[(rowbase + i0A + ii) * CC + hd + dof];
        *(uint4*)&QBh[ii][dof] = *(const uint4*)&Kh[(rowbase + i0B + ii) * CC + hd + dof];
        *(uint4*)&QBl[ii][dof] = *(const uint4*)&Kl[(rowbase + i0B + ii) * CC + hd + dof];
    }
    __syncthreads();

    // hoisted Q fragments
    const int qrow = w * 16 + l15;
    bf16x8 qAh0 = *(const bf16x8*)&QAh[qrow][quad * 8];
    bf16x8 qAh1 = *(const bf16x8*)&QAh[qrow][32 + quad * 8];
    bf16x8 qAl0 = *(const bf16x8*)&QAl[qrow][quad * 8];
    bf16x8 qAl1 = *(const bf16x8*)&QAl[qrow][32 + quad * 8];
    bf16x8 qBh0 = *(const bf16x8*)&QBh[qrow][quad * 8];
    bf16x8 qBh1 = *(const bf16x8*)&QBh[qrow][32 + quad * 8];
    bf16x8 qBl0 = *(const bf16x8*)&QBl[qrow][quad * 8];
    bf16x8 qBl1 = *(const bf16x8*)&QBl[qrow][32 + quad * 8];

    float mA[4], lA[4], mB[4], lB[4];
    f32x4 oA[4] = {}, oB[4] = {};
    #pragma unroll
    for (int r = 0; r < 4; ++r) { mA[r] = -1e30f; lA[r] = 0.f; mB[r] = -1e30f; lB[r] = 0.f; }

    const int jj0 = tid >> 3, df0 = (tid & 7) * 8;
    const int jj1 = (tid + 256) >> 3, df1 = ((tid + 256) & 7) * 8;
    uint4 pKh0, pKh1, pKl0, pKl1, pV0, pV1;

    // prefetch tile 0
    pKh0 = *(const uint4*)&Xh[(rowbase + jj0) * CC + hd + df0];
    pKh1 = *(const uint4*)&Xh[(rowbase + jj1) * CC + hd + df1];
    pKl0 = *(const uint4*)&Xl[(rowbase + jj0) * CC + hd + df0];
    pKl1 = *(const uint4*)&Xl[(rowbase + jj1) * CC + hd + df1];
    pV0  = *(const uint4*)&Vt[vbase + (size_t)jj0 * TT + df0];
    pV1  = *(const uint4*)&Vt[vbase + (size_t)jj1 * TT + df1];

    for (int jt = 0; jt <= iB; ++jt) {
        *(uint4*)&Ksh[jj0][df0] = pKh0;
        *(uint4*)&Ksh[jj1][df1] = pKh1;
        *(uint4*)&Ksl[jj0][df0] = pKl0;
        *(uint4*)&Ksl[jj1][df1] = pKl1;
        *(uint4*)&Vs[jj0][df0]  = pV0;
        *(uint4*)&Vs[jj1][df1]  = pV1;
        __syncthreads();

        if (jt < iB) {
            const int j0n = (jt + 1) * 64;
            pKh0 = *(const uint4*)&Xh[(rowbase + j0n + jj0) * CC + hd + df0];
            pKh1 = *(const uint4*)&Xh[(rowbase + j0n + jj1) * CC + hd + df1];
            pKl0 = *(const uint4*)&Xl[(rowbase + j0n + jj0) * CC + hd + df0];
            pKl1 = *(const uint4*)&Xl[(rowbase + j0n + jj1) * CC + hd + df1];
            pV0  = *(const uint4*)&Vt[vbase + (size_t)jj0 * TT + j0n + df0];
            pV1  = *(const uint4*)&Vt[vbase + (size_t)jj1 * TT + j0n + df1];
        }

        f32x4 s[4];
        // ---- tile B (always active) ----
        #pragma unroll
        for (int nt = 0; nt < 4; ++nt) {
            const int krow = nt * 16 + l15;
            bf16x8 kh0 = *(const bf16x8*)&Ksh[krow][quad * 8];
            bf16x8 kh1 = *(const bf16x8*)&Ksh[krow][32 + quad * 8];
            bf16x8 kl0 = *(const bf16x8*)&Ksl[krow][quad * 8];
            bf16x8 kl1 = *(const bf16x8*)&Ksl[krow][32 + quad * 8];
            f32x4 z = {};
            z = MFMA(qBh0, kl0, z);
            z = MFMA(qBl0, kh0, z);
            z = MFMA(qBh0, kh0, z);
            z = MFMA(qBh1, kl1, z);
            z = MFMA(qBl1, kh1, z);
            z = MFMA(qBh1, kh1, z);
            s[nt] = z;
        }
        if (jt == iB) {
            #pragma unroll
            for (int nt = 0; nt < 4; ++nt) {
                const int jg = nt * 16 + l15;
                #pragma unroll
                for (int r = 0; r < 4; ++r)
                    if (jg > w * 16 + quad * 4 + r) s[nt][r] = -1e30f;
            }
        }
        online_update(s, mB, lB, oB, Ps[w], Vs, quad, l15);

        // ---- tile A (early iterations only) ----
        if (jt <= iA) {
            #pragma unroll
            for (int nt = 0; nt < 4; ++nt) {
                const int krow = nt * 16 + l15;
                bf16x8 kh0 = *(const bf16x8*)&Ksh[krow][quad * 8];
                bf16x8 kh1 = *(const bf16x8*)&Ksh[krow][32 + quad * 8];
                bf16x8 kl0 = *(const bf16x8*)&Ksl[krow][quad * 8];
                bf16x8 kl1 = *(const bf16x8*)&Ksl[krow][32 + quad * 8];
                f32x4 z = {};
                z = MFMA(qAh0, kl0, z);
                z = MFMA(qAl0, kh0, z);
                z = MFMA(qAh0, kh0, z);
                z = MFMA(qAh1, kl1, z);
                z = MFMA(qAl1, kh1, z);
                z = MFMA(qAh1, kh1, z);
                s[nt] = z;
            }
            if (jt == iA) {
                #pragma unroll
                for (int nt = 0; nt < 4; ++nt) {
                    const int jg = nt * 16 + l15;
                    #pragma unroll
                    for (int r = 0; r < 4; ++r)
                        if (jg > w * 16 + quad * 4 + r) s[nt][r] = -1e30f;
                }
            }
            online_update(s, mA, lA, oA, Ps[w], Vs, quad, l15);
        }
        __syncthreads();
    }

    // epilogue
    #pragma unroll
    for (int dt = 0; dt < 4; ++dt) {
        #pragma unroll
        for (int r = 0; r < 4; ++r) {
            const int igA = i0A + w * 16 + quad * 4 + r;
            const int igB = i0B + w * 16 + quad * 4 + r;
            out[(rowbase + igA) * CC + hd + dt * 16 + l15] = oA[dt][r] / lA[r];
            out[(rowbase + igB) * CC + hd + dt * 16 + l15] = oB[dt][r] / lB[r];
        }
    }
}

extern "C" void kernel_launch(void* const* d_in, const int* in_sizes, int n_in,
                              void* d_out, int out_size, void* d_ws, size_t ws_size,
                              hipStream_t stream) {
    (void)in_sizes; (void)n_in; (void)out_size; (void)ws_size;
    const float* x  = (const float*)d_in[0];
    const float* Wk = (const float*)d_in[1];
    const float* bk = (const float*)d_in[2];
    const float* Wv = (const float*)d_in[3];
    const float* bv = (const float*)d_in[4];
    float* out = (float*)d_out;

    const size_t M4 = (size_t)BT * CC;   // 4M elements
    const size_t M1 = (size_t)CC * CC;   // 1M elements
    u16* Xh   = (u16*)d_ws;
    u16* Xl   = Xh + M4;
    u16* Kh   = Xl + M4;
    u16* Kl   = Kh + M4;
    u16* Vt   = Kl + M4;
    u16* WkTh = Vt + M4;
    u16* WkTl = WkTh + M1;
    u16* WvTh = WkTl + M1;               // total 46 MB

    convert_x<<<dim3(M4 / (256 * 8)), 256, 0, stream>>>(x, Xh, Xl);
    convert_w<<<dim3(16, 16, 2), 256, 0, stream>>>(Wk, Wv, WkTh, WkTl, WvTh);
    proj_kernel<<<dim3(8, 32, 2), 256, 0, stream>>>(
        Xh, Xl, WkTh, WkTl, WvTh, bk, bv, Kh, Kl, Vt);
    attn_kernel<<<dim3(16, NHH, BB), 256, 0, stream>>>(Xh, Xl, Kh, Kl, Vt, out);
}